// Round 8
// baseline (142.860 us; speedup 1.0000x reference)
//
#include <hip/hip_runtime.h>
#include <math.h>

#define N 256
#define NN (N * N)      // 65536
#define NNN (N * N * N) // 16777216
#define CH 4160         // chunk-record stride in floats (4096 + 64 pad for channel rotation)

__device__ inline float4 f4max(float4 a, float4 b) {
  return make_float4(fmaxf(a.x, b.x), fmaxf(a.y, b.y), fmaxf(a.z, b.z), fmaxf(a.w, b.w));
}
__device__ inline float4 f4add(float4 a, float4 b) {
  return make_float4(a.x + b.x, a.y + b.y, a.z + b.z, a.w + b.w);
}

// ===== reduce_bc: contiguous c-plane halves (dense reads, proven fast) =====
// block = (b, c, h-half): reads x[b, c, hh*128:(hh+1)*128, :] (128 KiB contiguous)
//   zB{hh}[b][c][w] = max/mean over its 128 h   (partials merged in conv)
//   zCT[b][c][h]    = max/mean over w           (complete rows, transposed layout)
__global__ __launch_bounds__(256) void reduce_bc_kernel(
    const float* __restrict__ x,
    float* __restrict__ zB0max, float* __restrict__ zB0mean,
    float* __restrict__ zB1max, float* __restrict__ zB1mean,
    float* __restrict__ zCTmax, float* __restrict__ zCTmean) {
  __shared__ float pms[128][9][2];
  __shared__ float gm[4][N];
  __shared__ float gs[4][N];
  const int lane = threadIdx.x & 63;
  const int g = threadIdx.x >> 6;
  const int hh = blockIdx.x & 1;
  const int bc = blockIdx.x >> 1;   // b*N + c
  const int b = bc >> 8, c = bc & 255;
  const float* p = x + (size_t)b * NNN + (size_t)c * NN +
                   (size_t)(hh * 128 + g * 32) * N + (lane << 2);
  float4 m4 = make_float4(-INFINITY, -INFINITY, -INFINITY, -INFINITY);
  float4 s4 = make_float4(0.f, 0.f, 0.f, 0.f);
#pragma unroll 4
  for (int i = 0; i < 32; ++i) {
    float4 v = *(const float4*)(p + (size_t)i * N);
    m4 = f4max(m4, v);
    s4 = f4add(s4, v);
    float m = fmaxf(fmaxf(v.x, v.y), fmaxf(v.z, v.w));
    float s = (v.x + v.y) + (v.z + v.w);
    m = fmaxf(m, __shfl_xor(m, 1));
    s += __shfl_xor(s, 1);
    m = fmaxf(m, __shfl_xor(m, 2));
    s += __shfl_xor(s, 2);
    m = fmaxf(m, __shfl_xor(m, 4));
    s += __shfl_xor(s, 4);
    if ((lane & 7) == 0) {
      const int l = g * 32 + i;
      pms[l][lane >> 3][0] = m;
      pms[l][lane >> 3][1] = s;
    }
  }
  const int w4 = lane << 2;
  *(float4*)&gm[g][w4] = m4;
  *(float4*)&gs[g][w4] = s4;
  __syncthreads();
  const int t = threadIdx.x;
  {
    float m = fmaxf(fmaxf(gm[0][t], gm[1][t]), fmaxf(gm[2][t], gm[3][t]));
    float s = (gs[0][t] + gs[1][t] + gs[2][t] + gs[3][t]) * (1.f / 256.f);
    float* zm = hh ? zB1max : zB0max;
    float* zs = hh ? zB1mean : zB0mean;
    zm[(size_t)bc * N + t] = m;
    zs[(size_t)bc * N + t] = s;
  }
  if (t < 128) {
    float m = pms[t][0][0];
    float s = pms[t][0][1];
#pragma unroll
    for (int i = 1; i < 8; ++i) {
      m = fmaxf(m, pms[t][i][0]);
      s += pms[t][i][1];
    }
    zCTmax[(size_t)bc * N + hh * 128 + t] = m;
    zCTmean[(size_t)bc * N + hh * 128 + t] = s * (1.f / 256.f);
  }
}

// ===== reduce_a_partial: c-reduction with 16KB full-channel bursts =====
// block = (b, chunk of 8 c's, 16KB subtile of the hw-plane).
// Per c: the block reads 16KB CONTIGUOUS (4 coalesced f4 loads). Register acc.
// Partial record layout (padded for channel rotation in the fold pass):
//   pm[((b*16+sub)*32+chunk)*CH + k*1024 + t*4]
__global__ __launch_bounds__(256) void reduce_a_partial_kernel(
    const float* __restrict__ x,
    float* __restrict__ pm, float* __restrict__ ps) {
  const int a = blockIdx.x;           // B*32*16
  const int sub = a & 15;
  const int chunk = (a >> 4) & 31;
  const int b = a >> 9;
  const int t = threadIdx.x;
  const float* base = x + (size_t)b * NNN + (size_t)(chunk * 8) * NN + sub * 4096 + (t << 2);
  float4 m0 = make_float4(-INFINITY, -INFINITY, -INFINITY, -INFINITY);
  float4 m1 = m0, m2 = m0, m3 = m0;
  float4 s0 = make_float4(0.f, 0.f, 0.f, 0.f);
  float4 s1 = s0, s2 = s0, s3 = s0;
#pragma unroll
  for (int c = 0; c < 8; ++c) {
    const float* p = base + (size_t)c * NN;
    float4 v0 = *(const float4*)(p);
    float4 v1 = *(const float4*)(p + 1024);
    float4 v2 = *(const float4*)(p + 2048);
    float4 v3 = *(const float4*)(p + 3072);
    m0 = f4max(m0, v0); s0 = f4add(s0, v0);
    m1 = f4max(m1, v1); s1 = f4add(s1, v1);
    m2 = f4max(m2, v2); s2 = f4add(s2, v2);
    m3 = f4max(m3, v3); s3 = f4add(s3, v3);
  }
  const size_t rec = (size_t)((b * 16 + sub) * 32 + chunk) * CH + (t << 2);
  *(float4*)(pm + rec + 0)    = m0;
  *(float4*)(pm + rec + 1024) = m1;
  *(float4*)(pm + rec + 2048) = m2;
  *(float4*)(pm + rec + 3072) = m3;
  *(float4*)(ps + rec + 0)    = s0;
  *(float4*)(ps + rec + 1024) = s1;
  *(float4*)(ps + rec + 2048) = s2;
  *(float4*)(ps + rec + 3072) = s3;
}

// ===== fold_a: fold 32 chunk partials -> zA[b][h][w] =====
// block = (b, sub, qtr): reads 4KB per chunk at 16.25KB stride (channel-rotating)
__global__ __launch_bounds__(256) void fold_a_kernel(
    const float* __restrict__ pm, const float* __restrict__ ps,
    float* __restrict__ zAmax, float* __restrict__ zAmean) {
  const int a = blockIdx.x;          // B*16*4
  const int qtr = a & 3;
  const int sub = (a >> 2) & 15;
  const int b = a >> 6;
  const int t = threadIdx.x;
  const size_t base = (size_t)(b * 16 + sub) * 32 * CH + qtr * 1024 + (t << 2);
  float4 m = make_float4(-INFINITY, -INFINITY, -INFINITY, -INFINITY);
  float4 s = make_float4(0.f, 0.f, 0.f, 0.f);
#pragma unroll 8
  for (int chunk = 0; chunk < 32; ++chunk) {
    const size_t o = base + (size_t)chunk * CH;
    m = f4max(m, *(const float4*)(pm + o));
    s = f4add(s, *(const float4*)(ps + o));
  }
  s.x *= (1.f / 256.f); s.y *= (1.f / 256.f); s.z *= (1.f / 256.f); s.w *= (1.f / 256.f);
  const size_t pos = (size_t)b * NN + sub * 4096 + qtr * 1024 + (t << 2);
  *(float4*)(zAmax + pos) = m;
  *(float4*)(zAmean + pos) = s;
}

// -------- fused 7x7 conv (2ch->1) + BN + sigmoid for ALL THREE gates --------
__global__ __launch_bounds__(256) void conv_gate3_kernel(
    const float* __restrict__ zAmax, const float* __restrict__ zAmean,
    const float* __restrict__ zB0max, const float* __restrict__ zB0mean,
    const float* __restrict__ zB1max, const float* __restrict__ zB1mean,
    const float* __restrict__ zCTmax, const float* __restrict__ zCTmean,
    const float* __restrict__ w_hw, const float* __restrict__ g_hw,
    const float* __restrict__ b_hw, const float* __restrict__ m_hw,
    const float* __restrict__ v_hw,
    const float* __restrict__ w_hc, const float* __restrict__ g_hc,
    const float* __restrict__ b_hc, const float* __restrict__ m_hc,
    const float* __restrict__ v_hc,
    const float* __restrict__ w_wc, const float* __restrict__ g_wc,
    const float* __restrict__ b_wc, const float* __restrict__ m_wc,
    const float* __restrict__ v_wc,
    float* __restrict__ Ghw, float* __restrict__ Ghc, float* __restrict__ Gwc,
    int BN) {
  const int branch = blockIdx.x / BN;
  const int bp = blockIdx.x - branch * BN;  // b*N + (p or c)
  const int b = bp >> 8;
  const size_t boff = (size_t)b * NN;

  if (branch == 2) {
    const int c = bp & 255;
    const int h = threadIdx.x;
    const float* zm = zCTmax + boff;
    const float* za = zCTmean + boff;
    float y = 0.f;
#pragma unroll
    for (int dc = 0; dc < 7; ++dc) {
      const int cc = c + dc - 3;
      if ((unsigned)cc < N) {
#pragma unroll
        for (int dh = 0; dh < 7; ++dh) {
          const int hh = h + dh - 3;
          if ((unsigned)hh < N) {
            const int idx = cc * N + hh;
            y += zm[idx] * w_wc[dh * 7 + dc] + za[idx] * w_wc[49 + dh * 7 + dc];
          }
        }
      }
    }
    const float scale = g_wc[0] * rsqrtf(v_wc[0] + 1e-5f);
    const float yb = (y - m_wc[0]) * scale + b_wc[0];
    Gwc[boff + (size_t)h * N + c] = 1.f / (1.f + __expf(-yb));
    return;
  }

  const int p = bp & 255;
  const int q = threadIdx.x;
  const float *zm0, *zm1, *za0, *za1;
  const float *wt, *gg, *bb, *mm, *vv;
  float* gate;
  bool dual;
  if (branch == 0) {
    zm0 = zAmax; zm1 = zAmax; za0 = zAmean; za1 = zAmean; dual = false;
    wt = w_hw; gg = g_hw; bb = b_hw; mm = m_hw; vv = v_hw; gate = Ghw;
  } else {
    zm0 = zB0max; zm1 = zB1max; za0 = zB0mean; za1 = zB1mean; dual = true;
    wt = w_hc; gg = g_hc; bb = b_hc; mm = m_hc; vv = v_hc; gate = Ghc;
  }
  zm0 += boff; zm1 += boff; za0 += boff; za1 += boff;
  float y = 0.f;
#pragma unroll
  for (int dh = 0; dh < 7; ++dh) {
    const int pp = p + dh - 3;
    if ((unsigned)pp < N) {
#pragma unroll
      for (int dw = 0; dw < 7; ++dw) {
        const int qq = q + dw - 3;
        if ((unsigned)qq < N) {
          const int idx = pp * N + qq;
          const float zm = dual ? fmaxf(zm0[idx], zm1[idx]) : zm0[idx];
          const float za = dual ? (za0[idx] + za1[idx]) : za0[idx];
          y += zm * wt[dh * 7 + dw] + za * wt[49 + dh * 7 + dw];
        }
      }
    }
  }
  const float scale = gg[0] * rsqrtf(vv[0] + 1e-5f);
  const float yb = (y - mm[0]) * scale + bb[0];
  gate[boff + (size_t)p * N + q] = 1.f / (1.f + __expf(-yb));
}

// -------- final combine --------
// out[b,i,j,k] = ( x[b,i,j,k]*(Ghw[b,j,k]+Ghc[b,i,k]) + x[b,k,i,j]*Gwc[b,i,k] ) / 3
__global__ __launch_bounds__(256) void combine_kernel(
    const float* __restrict__ x, const float* __restrict__ Ghw,
    const float* __restrict__ Ghc, const float* __restrict__ Gwc,
    float* __restrict__ out) {
  __shared__ float t[32][33];
  const int blk = blockIdx.x;
  const int kt = blk & 7, jt = (blk >> 3) & 7, i = (blk >> 6) & 255, b = blk >> 14;
  const int k0 = kt << 5, j0 = jt << 5;
  const int rowi = threadIdx.x >> 3;
  const int col4 = (threadIdx.x & 7) << 2;
  {
    float4 v = *(const float4*)(x + ((size_t)b << 24) + ((size_t)(k0 + rowi) << 16) +
                                ((size_t)i << 8) + j0 + col4);
    t[rowi][col4 + 0] = v.x;
    t[rowi][col4 + 1] = v.y;
    t[rowi][col4 + 2] = v.z;
    t[rowi][col4 + 3] = v.w;
  }
  __syncthreads();
  const int jj = rowi;
  const int k = k0 + col4;
  const size_t gik = (((size_t)(b << 8) + i) << 8) + k;
  const float4 ghc = *(const float4*)(Ghc + gik);
  const float4 gwc = *(const float4*)(Gwc + gik);
  const size_t base = ((size_t)b << 24) + ((size_t)i << 16) + ((size_t)(j0 + jj) << 8) + k;
  const float4 xv = *(const float4*)(x + base);
  const float4 ghw = *(const float4*)(Ghw + ((size_t)b << 16) + ((size_t)(j0 + jj) << 8) + k);
  const float third = 1.f / 3.f;
  float4 r;
  r.x = (xv.x * (ghw.x + ghc.x) + t[col4 + 0][jj] * gwc.x) * third;
  r.y = (xv.y * (ghw.y + ghc.y) + t[col4 + 1][jj] * gwc.y) * third;
  r.z = (xv.z * (ghw.z + ghc.z) + t[col4 + 2][jj] * gwc.z) * third;
  r.w = (xv.w * (ghw.w + ghc.w) + t[col4 + 3][jj] * gwc.w) * third;
  *(float4*)(out + base) = r;
}

extern "C" void kernel_launch(void* const* d_in, const int* in_sizes, int n_in,
                              void* d_out, int out_size, void* d_ws, size_t ws_size,
                              hipStream_t stream) {
  const float* x    = (const float*)d_in[0];
  const float* w_hw = (const float*)d_in[1];
  const float* g_hw = (const float*)d_in[2];
  const float* b_hw = (const float*)d_in[3];
  const float* m_hw = (const float*)d_in[4];
  const float* v_hw = (const float*)d_in[5];
  const float* w_hc = (const float*)d_in[6];
  const float* g_hc = (const float*)d_in[7];
  const float* b_hc = (const float*)d_in[8];
  const float* m_hc = (const float*)d_in[9];
  const float* v_hc = (const float*)d_in[10];
  const float* w_wc = (const float*)d_in[11];
  const float* g_wc = (const float*)d_in[12];
  const float* b_wc = (const float*)d_in[13];
  const float* m_wc = (const float*)d_in[14];
  const float* v_wc = (const float*)d_in[15];

  const int B = in_sizes[0] / NNN; // 2
  const int BN = B * N;
  const size_t plane = (size_t)B * NN;
  float* ws = (float*)d_ws;
  float* zB0max  = ws + 0 * plane;
  float* zB0mean = ws + 1 * plane;
  float* zB1max  = ws + 2 * plane;
  float* zB1mean = ws + 3 * plane;
  float* zCTmax  = ws + 4 * plane;
  float* zCTmean = ws + 5 * plane;
  float* zAmax   = ws + 6 * plane;
  float* zAmean  = ws + 7 * plane;
  float* GhwP    = ws + 8 * plane;
  float* GhcP    = ws + 9 * plane;
  float* GwcP    = ws + 10 * plane;

  // zA chunk partials parked in d_out (consumed by fold_a before combine overwrites)
  float* pm = (float*)d_out;
  float* ps = pm + (size_t)B * 16 * 32 * CH;

  reduce_bc_kernel<<<2 * BN, 256, 0, stream>>>(
      x, zB0max, zB0mean, zB1max, zB1mean, zCTmax, zCTmean);
  reduce_a_partial_kernel<<<B * 32 * 16, 256, 0, stream>>>(x, pm, ps);
  fold_a_kernel<<<B * 16 * 4, 256, 0, stream>>>(pm, ps, zAmax, zAmean);

  conv_gate3_kernel<<<3 * BN, 256, 0, stream>>>(
      zAmax, zAmean, zB0max, zB0mean, zB1max, zB1mean, zCTmax, zCTmean,
      w_hw, g_hw, b_hw, m_hw, v_hw,
      w_hc, g_hc, b_hc, m_hc, v_hc,
      w_wc, g_wc, b_wc, m_wc, v_wc,
      GhwP, GhcP, GwcP, BN);

  combine_kernel<<<B * N * 64, 256, 0, stream>>>(x, GhwP, GhcP, GwcP, (float*)d_out);
}

// Round 9
// 131.420 us; speedup vs baseline: 1.0870x; 1.0870x over previous
//
#include <hip/hip_runtime.h>
#include <math.h>

#define N 256
#define NN (N * N)      // 65536
#define NNN (N * N * N) // 16777216

__device__ inline float4 f4max(float4 a, float4 b) {
  return make_float4(fmaxf(a.x, b.x), fmaxf(a.y, b.y), fmaxf(a.z, b.z), fmaxf(a.w, b.w));
}
__device__ inline float4 f4add(float4 a, float4 b) {
  return make_float4(a.x + b.x, a.y + b.y, a.z + b.z, a.w + b.w);
}

// ===== reduce_bc: contiguous c-plane halves (dense reads) =====
// block = (b, c, h-half): reads x[b, c, hh*128:(hh+1)*128, :] (128 KiB contiguous)
//   zB{hh}[b][c][w] = max/mean over its 128 h   (partials merged in conv)
//   zCT[b][c][h]    = max/mean over w           (complete rows, transposed layout)
// Runs FIRST: pulls x into L3 for the tile-gather pass.
__global__ __launch_bounds__(256) void reduce_bc_kernel(
    const float* __restrict__ x,
    float* __restrict__ zB0max, float* __restrict__ zB0mean,
    float* __restrict__ zB1max, float* __restrict__ zB1mean,
    float* __restrict__ zCTmax, float* __restrict__ zCTmean) {
  __shared__ float pms[128][9][2];
  __shared__ float gm[4][N];
  __shared__ float gs[4][N];
  const int lane = threadIdx.x & 63;
  const int g = threadIdx.x >> 6;
  const int hh = blockIdx.x & 1;
  const int bc = blockIdx.x >> 1;   // b*N + c
  const int b = bc >> 8, c = bc & 255;
  const float* p = x + (size_t)b * NNN + (size_t)c * NN +
                   (size_t)(hh * 128 + g * 32) * N + (lane << 2);
  float4 m4 = make_float4(-INFINITY, -INFINITY, -INFINITY, -INFINITY);
  float4 s4 = make_float4(0.f, 0.f, 0.f, 0.f);
#pragma unroll 4
  for (int i = 0; i < 32; ++i) {
    float4 v = *(const float4*)(p + (size_t)i * N);
    m4 = f4max(m4, v);
    s4 = f4add(s4, v);
    float m = fmaxf(fmaxf(v.x, v.y), fmaxf(v.z, v.w));
    float s = (v.x + v.y) + (v.z + v.w);
    m = fmaxf(m, __shfl_xor(m, 1));
    s += __shfl_xor(s, 1);
    m = fmaxf(m, __shfl_xor(m, 2));
    s += __shfl_xor(s, 2);
    m = fmaxf(m, __shfl_xor(m, 4));
    s += __shfl_xor(s, 4);
    if ((lane & 7) == 0) {
      const int l = g * 32 + i;
      pms[l][lane >> 3][0] = m;
      pms[l][lane >> 3][1] = s;
    }
  }
  const int w4 = lane << 2;
  *(float4*)&gm[g][w4] = m4;
  *(float4*)&gs[g][w4] = s4;
  __syncthreads();
  const int t = threadIdx.x;
  {
    float m = fmaxf(fmaxf(gm[0][t], gm[1][t]), fmaxf(gm[2][t], gm[3][t]));
    float s = (gs[0][t] + gs[1][t] + gs[2][t] + gs[3][t]) * (1.f / 256.f);
    float* zm = hh ? zB1max : zB0max;
    float* zs = hh ? zB1mean : zB0mean;
    zm[(size_t)bc * N + t] = m;
    zs[(size_t)bc * N + t] = s;
  }
  if (t < 128) {
    float m = pms[t][0][0];
    float s = pms[t][0][1];
#pragma unroll
    for (int i = 1; i < 8; ++i) {
      m = fmaxf(m, pms[t][i][0]);
      s += pms[t][i][1];
    }
    zCTmax[(size_t)bc * N + hh * 128 + t] = m;
    zCTmean[(size_t)bc * N + hh * 128 + t] = s * (1.f / 256.f);
  }
}

// ===== reduce_a_tile: zA c-reduction in the combine-proven tile pattern =====
// grid = B*256*8*8 (32768 short blocks). Block (b, i=h, jt, kt): stage the
// 32x32 (c x w) tile x[b, k0+kk, i, j0+jj] (one float4 per thread), fold over
// kk (c) in LDS, write 32 (m,s) partials.
// pA layout: [((b*256+i)*8 + kt)*256 + j]  (8 c-tile partials per (b,h))
__global__ __launch_bounds__(256) void reduce_a_tile_kernel(
    const float* __restrict__ x,
    float* __restrict__ pAm, float* __restrict__ pAs) {
  __shared__ float t[32][33];
  __shared__ float pm2[8][33];
  __shared__ float ps2[8][33];
  const int blk = blockIdx.x;
  const int kt = blk & 7, jt = (blk >> 3) & 7, i = (blk >> 6) & 255, b = blk >> 14;
  const int k0 = kt << 5, j0 = jt << 5;
  const int rowi = threadIdx.x >> 3;        // 0..31 (c within tile)
  const int col4 = (threadIdx.x & 7) << 2;  // 0,4,...,28 (w within tile)
  {
    float4 v = *(const float4*)(x + ((size_t)b << 24) + ((size_t)(k0 + rowi) << 16) +
                                ((size_t)i << 8) + j0 + col4);
    t[rowi][col4 + 0] = v.x;
    t[rowi][col4 + 1] = v.y;
    t[rowi][col4 + 2] = v.z;
    t[rowi][col4 + 3] = v.w;
  }
  __syncthreads();
  // two-level fold over kk: 8 groups of 4, then 8 -> 1
  const int jj = threadIdx.x & 31;
  const int kg = threadIdx.x >> 5;  // 0..7
  {
    float f0 = t[kg * 4 + 0][jj];
    float f1 = t[kg * 4 + 1][jj];
    float f2 = t[kg * 4 + 2][jj];
    float f3 = t[kg * 4 + 3][jj];
    pm2[kg][jj] = fmaxf(fmaxf(f0, f1), fmaxf(f2, f3));
    ps2[kg][jj] = (f0 + f1) + (f2 + f3);
  }
  __syncthreads();
  if (threadIdx.x < 32) {
    float m = pm2[0][jj], s = ps2[0][jj];
#pragma unroll
    for (int q = 1; q < 8; ++q) {
      m = fmaxf(m, pm2[q][jj]);
      s += ps2[q][jj];
    }
    const size_t o = (((size_t)(b << 8) + i) * 8 + kt) * N + j0 + jj;
    pAm[o] = m;
    pAs[o] = s;
  }
}

// ===== fold_a: fold the 8 c-tile partials -> zA[b][h][w] =====
__global__ __launch_bounds__(256) void fold_a_kernel(
    const float* __restrict__ pAm, const float* __restrict__ pAs,
    float* __restrict__ zAmax, float* __restrict__ zAmean) {
  const int bh = blockIdx.x;   // b*N + h
  const int w = threadIdx.x;
  const float* pm = pAm + (size_t)bh * 8 * N + w;
  const float* ps = pAs + (size_t)bh * 8 * N + w;
  float m = pm[0], s = ps[0];
#pragma unroll
  for (int ct = 1; ct < 8; ++ct) {
    m = fmaxf(m, pm[ct * N]);
    s += ps[ct * N];
  }
  zAmax[(size_t)bh * N + w] = m;
  zAmean[(size_t)bh * N + w] = s * (1.f / 256.f);
}

// -------- fused 7x7 conv (2ch->1) + BN + sigmoid for ALL THREE gates --------
__global__ __launch_bounds__(256) void conv_gate3_kernel(
    const float* __restrict__ zAmax, const float* __restrict__ zAmean,
    const float* __restrict__ zB0max, const float* __restrict__ zB0mean,
    const float* __restrict__ zB1max, const float* __restrict__ zB1mean,
    const float* __restrict__ zCTmax, const float* __restrict__ zCTmean,
    const float* __restrict__ w_hw, const float* __restrict__ g_hw,
    const float* __restrict__ b_hw, const float* __restrict__ m_hw,
    const float* __restrict__ v_hw,
    const float* __restrict__ w_hc, const float* __restrict__ g_hc,
    const float* __restrict__ b_hc, const float* __restrict__ m_hc,
    const float* __restrict__ v_hc,
    const float* __restrict__ w_wc, const float* __restrict__ g_wc,
    const float* __restrict__ b_wc, const float* __restrict__ m_wc,
    const float* __restrict__ v_wc,
    float* __restrict__ Ghw, float* __restrict__ Ghc, float* __restrict__ Gwc,
    int BN) {
  const int branch = blockIdx.x / BN;
  const int bp = blockIdx.x - branch * BN;  // b*N + (p or c)
  const int b = bp >> 8;
  const size_t boff = (size_t)b * NN;

  if (branch == 2) {
    const int c = bp & 255;
    const int h = threadIdx.x;
    const float* zm = zCTmax + boff;
    const float* za = zCTmean + boff;
    float y = 0.f;
#pragma unroll
    for (int dc = 0; dc < 7; ++dc) {
      const int cc = c + dc - 3;
      if ((unsigned)cc < N) {
#pragma unroll
        for (int dh = 0; dh < 7; ++dh) {
          const int hh = h + dh - 3;
          if ((unsigned)hh < N) {
            const int idx = cc * N + hh;
            y += zm[idx] * w_wc[dh * 7 + dc] + za[idx] * w_wc[49 + dh * 7 + dc];
          }
        }
      }
    }
    const float scale = g_wc[0] * rsqrtf(v_wc[0] + 1e-5f);
    const float yb = (y - m_wc[0]) * scale + b_wc[0];
    Gwc[boff + (size_t)h * N + c] = 1.f / (1.f + __expf(-yb));
    return;
  }

  const int p = bp & 255;
  const int q = threadIdx.x;
  const float *zm0, *zm1, *za0, *za1;
  const float *wt, *gg, *bb, *mm, *vv;
  float* gate;
  bool dual;
  if (branch == 0) {
    zm0 = zAmax; zm1 = zAmax; za0 = zAmean; za1 = zAmean; dual = false;
    wt = w_hw; gg = g_hw; bb = b_hw; mm = m_hw; vv = v_hw; gate = Ghw;
  } else {
    zm0 = zB0max; zm1 = zB1max; za0 = zB0mean; za1 = zB1mean; dual = true;
    wt = w_hc; gg = g_hc; bb = b_hc; mm = m_hc; vv = v_hc; gate = Ghc;
  }
  zm0 += boff; zm1 += boff; za0 += boff; za1 += boff;
  float y = 0.f;
#pragma unroll
  for (int dh = 0; dh < 7; ++dh) {
    const int pp = p + dh - 3;
    if ((unsigned)pp < N) {
#pragma unroll
      for (int dw = 0; dw < 7; ++dw) {
        const int qq = q + dw - 3;
        if ((unsigned)qq < N) {
          const int idx = pp * N + qq;
          const float zm = dual ? fmaxf(zm0[idx], zm1[idx]) : zm0[idx];
          const float za = dual ? (za0[idx] + za1[idx]) : za0[idx];
          y += zm * wt[dh * 7 + dw] + za * wt[49 + dh * 7 + dw];
        }
      }
    }
  }
  const float scale = gg[0] * rsqrtf(vv[0] + 1e-5f);
  const float yb = (y - mm[0]) * scale + bb[0];
  gate[boff + (size_t)p * N + q] = 1.f / (1.f + __expf(-yb));
}

// -------- final combine --------
// out[b,i,j,k] = ( x[b,i,j,k]*(Ghw[b,j,k]+Ghc[b,i,k]) + x[b,k,i,j]*Gwc[b,i,k] ) / 3
__global__ __launch_bounds__(256) void combine_kernel(
    const float* __restrict__ x, const float* __restrict__ Ghw,
    const float* __restrict__ Ghc, const float* __restrict__ Gwc,
    float* __restrict__ out) {
  __shared__ float t[32][33];
  const int blk = blockIdx.x;
  const int kt = blk & 7, jt = (blk >> 3) & 7, i = (blk >> 6) & 255, b = blk >> 14;
  const int k0 = kt << 5, j0 = jt << 5;
  const int rowi = threadIdx.x >> 3;
  const int col4 = (threadIdx.x & 7) << 2;
  {
    float4 v = *(const float4*)(x + ((size_t)b << 24) + ((size_t)(k0 + rowi) << 16) +
                                ((size_t)i << 8) + j0 + col4);
    t[rowi][col4 + 0] = v.x;
    t[rowi][col4 + 1] = v.y;
    t[rowi][col4 + 2] = v.z;
    t[rowi][col4 + 3] = v.w;
  }
  __syncthreads();
  const int jj = rowi;
  const int k = k0 + col4;
  const size_t gik = (((size_t)(b << 8) + i) << 8) + k;
  const float4 ghc = *(const float4*)(Ghc + gik);
  const float4 gwc = *(const float4*)(Gwc + gik);
  const size_t base = ((size_t)b << 24) + ((size_t)i << 16) + ((size_t)(j0 + jj) << 8) + k;
  const float4 xv = *(const float4*)(x + base);
  const float4 ghw = *(const float4*)(Ghw + ((size_t)b << 16) + ((size_t)(j0 + jj) << 8) + k);
  const float third = 1.f / 3.f;
  float4 r;
  r.x = (xv.x * (ghw.x + ghc.x) + t[col4 + 0][jj] * gwc.x) * third;
  r.y = (xv.y * (ghw.y + ghc.y) + t[col4 + 1][jj] * gwc.y) * third;
  r.z = (xv.z * (ghw.z + ghc.z) + t[col4 + 2][jj] * gwc.z) * third;
  r.w = (xv.w * (ghw.w + ghc.w) + t[col4 + 3][jj] * gwc.w) * third;
  *(float4*)(out + base) = r;
}

extern "C" void kernel_launch(void* const* d_in, const int* in_sizes, int n_in,
                              void* d_out, int out_size, void* d_ws, size_t ws_size,
                              hipStream_t stream) {
  const float* x    = (const float*)d_in[0];
  const float* w_hw = (const float*)d_in[1];
  const float* g_hw = (const float*)d_in[2];
  const float* b_hw = (const float*)d_in[3];
  const float* m_hw = (const float*)d_in[4];
  const float* v_hw = (const float*)d_in[5];
  const float* w_hc = (const float*)d_in[6];
  const float* g_hc = (const float*)d_in[7];
  const float* b_hc = (const float*)d_in[8];
  const float* m_hc = (const float*)d_in[9];
  const float* v_hc = (const float*)d_in[10];
  const float* w_wc = (const float*)d_in[11];
  const float* g_wc = (const float*)d_in[12];
  const float* b_wc = (const float*)d_in[13];
  const float* m_wc = (const float*)d_in[14];
  const float* v_wc = (const float*)d_in[15];

  const int B = in_sizes[0] / NNN; // 2
  const int BN = B * N;
  const size_t plane = (size_t)B * NN;
  float* ws = (float*)d_ws;
  float* zB0max  = ws + 0 * plane;
  float* zB0mean = ws + 1 * plane;
  float* zB1max  = ws + 2 * plane;
  float* zB1mean = ws + 3 * plane;
  float* zCTmax  = ws + 4 * plane;
  float* zCTmean = ws + 5 * plane;
  float* zAmax   = ws + 6 * plane;
  float* zAmean  = ws + 7 * plane;
  float* GhwP    = ws + 8 * plane;
  float* GhcP    = ws + 9 * plane;
  float* GwcP    = ws + 10 * plane;

  // zA c-tile partials parked in d_out (8 MB; consumed before combine overwrites)
  float* pAm = (float*)d_out;
  float* pAs = pAm + (size_t)BN * 8 * N;

  reduce_bc_kernel<<<2 * BN, 256, 0, stream>>>(
      x, zB0max, zB0mean, zB1max, zB1mean, zCTmax, zCTmean);
  reduce_a_tile_kernel<<<B * N * 64, 256, 0, stream>>>(x, pAm, pAs);
  fold_a_kernel<<<BN, 256, 0, stream>>>(pAm, pAs, zAmax, zAmean);

  conv_gate3_kernel<<<3 * BN, 256, 0, stream>>>(
      zAmax, zAmean, zB0max, zB0mean, zB1max, zB1mean, zCTmax, zCTmean,
      w_hw, g_hw, b_hw, m_hw, v_hw,
      w_hc, g_hc, b_hc, m_hc, v_hc,
      w_wc, g_wc, b_wc, m_wc, v_wc,
      GhwP, GhcP, GwcP, BN);

  combine_kernel<<<B * N * 64, 256, 0, stream>>>(x, GhwP, GhcP, GwcP, (float*)d_out);
}

// Round 10
// 130.422 us; speedup vs baseline: 1.0954x; 1.0077x over previous
//
#include <hip/hip_runtime.h>
#include <math.h>

#define N 256
#define NN (N * N)      // 65536
#define NNN (N * N * N) // 16777216

__device__ inline float4 f4max(float4 a, float4 b) {
  return make_float4(fmaxf(a.x, b.x), fmaxf(a.y, b.y), fmaxf(a.z, b.z), fmaxf(a.w, b.w));
}
__device__ inline float4 f4add(float4 a, float4 b) {
  return make_float4(a.x + b.x, a.y + b.y, a.z + b.z, a.w + b.w);
}

// ===== reduce_dense: ONE dense pass over x produces all three reductions =====
// block = (b, cg in [0,32), hb in [0,8)): covers c in [8cg, 8cg+8), h in [32hb, 32hb+32).
// Per c: 4 waves together read 32 consecutive rows (32 KB contiguous), then jump
// to the next c-plane. All x-reads are dense bursts.
//   zA: elementwise (over c) max/sum in REGISTERS (8 rows x f4 x 2 per thread)
//       -> pA[b][cg][ms][h][w] partials (fold over 32 cg in fold_a)
//   zB: per-wave fold over its 8 rows (regs) -> LDS fold over 4 waves
//       -> pB[b][c][hb][ms][w] partials (fold over 8 hb in fold_b)
//   zCT: per-row w-fold (3 shfl levels -> 8 partials in LDS) -> complete
//       zCT[b][c][h] (transposed layout for conv branch 2)
__global__ __launch_bounds__(256) void reduce_dense_kernel(
    const float* __restrict__ x,
    float* __restrict__ pA, float* __restrict__ pB,
    float* __restrict__ zCTmax, float* __restrict__ zCTmean) {
  __shared__ float pms[256][9][2];  // [c*32+h_local][8 w-partials pad 9][m,s]
  __shared__ float bf[4][2][N];     // zB cross-wave fold buffer (per c)
  const int t = threadIdx.x;
  const int lane = t & 63;
  const int g = t >> 6;
  const int blk = blockIdx.x;       // b*256 + cg*8 + hb
  const int hb = blk & 7;
  const int cg = (blk >> 3) & 31;
  const int b = blk >> 8;
  const int c0 = cg << 3;
  const int h0 = hb << 5;
  const int w4 = lane << 2;
  const float* base = x + (size_t)b * NNN + (size_t)c0 * NN +
                      (size_t)(h0 + g * 8) * N + w4;

  const float4 NEG = make_float4(-INFINITY, -INFINITY, -INFINITY, -INFINITY);
  const float4 ZERO = make_float4(0.f, 0.f, 0.f, 0.f);
  float4 am[8], as[8];   // zA elementwise acc per local row
  float4 zbm[8], zbs[8]; // zB per-wave fold per c
#pragma unroll
  for (int r = 0; r < 8; ++r) { am[r] = NEG; as[r] = ZERO; }

#pragma unroll
  for (int c = 0; c < 8; ++c) {
    const float* pc = base + (size_t)c * NN;
    float4 v[8];
#pragma unroll
    for (int r = 0; r < 8; ++r) v[r] = *(const float4*)(pc + (size_t)r * N);
    // zA elementwise acc
#pragma unroll
    for (int r = 0; r < 8; ++r) {
      am[r] = f4max(am[r], v[r]);
      as[r] = f4add(as[r], v[r]);
    }
    // zB within-wave fold over 8 rows
    {
      float4 bm = f4max(f4max(v[0], v[1]), f4max(v[2], v[3]));
      bm = f4max(bm, f4max(f4max(v[4], v[5]), f4max(v[6], v[7])));
      float4 bs = f4add(f4add(v[0], v[1]), f4add(v[2], v[3]));
      bs = f4add(bs, f4add(f4add(v[4], v[5]), f4add(v[6], v[7])));
      zbm[c] = bm;
      zbs[c] = bs;
    }
    // zCT per-row partials
#pragma unroll
    for (int r = 0; r < 8; ++r) {
      float m = fmaxf(fmaxf(v[r].x, v[r].y), fmaxf(v[r].z, v[r].w));
      float s = (v[r].x + v[r].y) + (v[r].z + v[r].w);
      m = fmaxf(m, __shfl_xor(m, 1));
      s += __shfl_xor(s, 1);
      m = fmaxf(m, __shfl_xor(m, 2));
      s += __shfl_xor(s, 2);
      m = fmaxf(m, __shfl_xor(m, 4));
      s += __shfl_xor(s, 4);
      if ((lane & 7) == 0) {
        const int row = c * 32 + g * 8 + r;  // 0..255
        pms[row][lane >> 3][0] = m;
        pms[row][lane >> 3][1] = s;
      }
    }
  }

  // --- write zA partials (coalesced, registers -> global) ---
  {
    const size_t oA = ((size_t)(b * 32 + cg) * 2) * NN + (size_t)(h0 + g * 8) * N + w4;
#pragma unroll
    for (int r = 0; r < 8; ++r) {
      *(float4*)(pA + oA + (size_t)r * N) = am[r];
      *(float4*)(pA + oA + NN + (size_t)r * N) = as[r];
    }
  }

  // --- zB cross-wave fold, c at a time ---
#pragma unroll
  for (int c = 0; c < 8; ++c) {
    *(float4*)&bf[g][0][w4] = zbm[c];
    *(float4*)&bf[g][1][w4] = zbs[c];
    __syncthreads();
    {
      float m = fmaxf(fmaxf(bf[0][0][t], bf[1][0][t]), fmaxf(bf[2][0][t], bf[3][0][t]));
      float s = bf[0][1][t] + bf[1][1][t] + bf[2][1][t] + bf[3][1][t];
      const size_t o = (((size_t)(b * N + c0 + c) * 8 + hb) * 2) * N + t;
      pB[o] = m;
      pB[o + N] = s;
    }
    __syncthreads();
  }

  // --- zCT finalize: thread t = row (c = t>>5, h_local = t&31) ---
  {
    float m = pms[t][0][0];
    float s = pms[t][0][1];
#pragma unroll
    for (int i = 1; i < 8; ++i) {
      m = fmaxf(m, pms[t][i][0]);
      s += pms[t][i][1];
    }
    const size_t o = (size_t)(b * N + c0 + (t >> 5)) * N + h0 + (t & 31);
    zCTmax[o] = m;
    zCTmean[o] = s * (1.f / 256.f);
  }
}

// ===== fold_a: fold 32 cg partials -> zA[b][h][w] =====
// thread-per-float; 512 short blocks; reads 32 MB at 512 KB stride.
__global__ __launch_bounds__(256) void fold_a_kernel(
    const float* __restrict__ pA,
    float* __restrict__ zAmax, float* __restrict__ zAmean) {
  const int idx = blockIdx.x * 256 + threadIdx.x;  // B*NN threads
  const int w = idx & 255;
  const int h = (idx >> 8) & 255;
  const int b = idx >> 16;
  const float* pm = pA + ((size_t)b * 32 * 2) * NN + (size_t)h * N + w;
  const float* ps = pm + NN;
  float m = pm[0];
  float s = ps[0];
#pragma unroll 8
  for (int cg = 1; cg < 32; ++cg) {
    const size_t o = (size_t)cg * 2 * NN;
    m = fmaxf(m, pm[o]);
    s += ps[o];
  }
  zAmax[(size_t)(b * N + h) * N + w] = m;
  zAmean[(size_t)(b * N + h) * N + w] = s * (1.f / 256.f);
}

// ===== fold_b: fold 8 hb partials -> zB[b][c][w] =====
__global__ __launch_bounds__(256) void fold_b_kernel(
    const float* __restrict__ pB,
    float* __restrict__ zBmax, float* __restrict__ zBmean) {
  const int bc = blockIdx.x;   // b*N + c
  const int w = threadIdx.x;
  const float* p = pB + ((size_t)bc * 8 * 2) * N + w;
  float m = p[0];
  float s = p[N];
#pragma unroll
  for (int hb = 1; hb < 8; ++hb) {
    m = fmaxf(m, p[(size_t)hb * 2 * N]);
    s += p[(size_t)hb * 2 * N + N];
  }
  zBmax[(size_t)bc * N + w] = m;
  zBmean[(size_t)bc * N + w] = s * (1.f / 256.f);
}

// -------- fused 7x7 conv (2ch->1) + BN + sigmoid for ALL THREE gates --------
// branch 0 (hw): zA in [b][h][w], out Ghw[b][h][w]
// branch 1 (hc): zB in [b][c][w], out Ghc[b][c][w]
// branch 2 (wc): zCT TRANSPOSED [b][c][h]; block=(b,c), thread=h, out Gwc[b][h][c]
__global__ __launch_bounds__(256) void conv_gate3_kernel(
    const float* __restrict__ zAmax, const float* __restrict__ zAmean,
    const float* __restrict__ zBmax, const float* __restrict__ zBmean,
    const float* __restrict__ zCTmax, const float* __restrict__ zCTmean,
    const float* __restrict__ w_hw, const float* __restrict__ g_hw,
    const float* __restrict__ b_hw, const float* __restrict__ m_hw,
    const float* __restrict__ v_hw,
    const float* __restrict__ w_hc, const float* __restrict__ g_hc,
    const float* __restrict__ b_hc, const float* __restrict__ m_hc,
    const float* __restrict__ v_hc,
    const float* __restrict__ w_wc, const float* __restrict__ g_wc,
    const float* __restrict__ b_wc, const float* __restrict__ m_wc,
    const float* __restrict__ v_wc,
    float* __restrict__ Ghw, float* __restrict__ Ghc, float* __restrict__ Gwc,
    int BN) {
  const int branch = blockIdx.x / BN;
  const int bp = blockIdx.x - branch * BN;  // b*N + (p or c)
  const int b = bp >> 8;
  const size_t boff = (size_t)b * NN;

  if (branch == 2) {
    const int c = bp & 255;
    const int h = threadIdx.x;
    const float* zm = zCTmax + boff;
    const float* za = zCTmean + boff;
    float y = 0.f;
#pragma unroll
    for (int dc = 0; dc < 7; ++dc) {
      const int cc = c + dc - 3;
      if ((unsigned)cc < N) {
#pragma unroll
        for (int dh = 0; dh < 7; ++dh) {
          const int hh = h + dh - 3;
          if ((unsigned)hh < N) {
            const int idx = cc * N + hh;
            y += zm[idx] * w_wc[dh * 7 + dc] + za[idx] * w_wc[49 + dh * 7 + dc];
          }
        }
      }
    }
    const float scale = g_wc[0] * rsqrtf(v_wc[0] + 1e-5f);
    const float yb = (y - m_wc[0]) * scale + b_wc[0];
    Gwc[boff + (size_t)h * N + c] = 1.f / (1.f + __expf(-yb));
    return;
  }

  const int p = bp & 255;
  const int q = threadIdx.x;
  const float *zm, *za, *wt, *gg, *bb, *mm, *vv;
  float* gate;
  if (branch == 0) {
    zm = zAmax; za = zAmean;
    wt = w_hw; gg = g_hw; bb = b_hw; mm = m_hw; vv = v_hw; gate = Ghw;
  } else {
    zm = zBmax; za = zBmean;
    wt = w_hc; gg = g_hc; bb = b_hc; mm = m_hc; vv = v_hc; gate = Ghc;
  }
  zm += boff;
  za += boff;
  float y = 0.f;
#pragma unroll
  for (int dh = 0; dh < 7; ++dh) {
    const int pp = p + dh - 3;
    if ((unsigned)pp < N) {
#pragma unroll
      for (int dw = 0; dw < 7; ++dw) {
        const int qq = q + dw - 3;
        if ((unsigned)qq < N) {
          const int idx = pp * N + qq;
          y += zm[idx] * wt[dh * 7 + dw] + za[idx] * wt[49 + dh * 7 + dw];
        }
      }
    }
  }
  const float scale = gg[0] * rsqrtf(vv[0] + 1e-5f);
  const float yb = (y - mm[0]) * scale + bb[0];
  gate[boff + (size_t)p * N + q] = 1.f / (1.f + __expf(-yb));
}

// -------- final combine --------
// out[b,i,j,k] = ( x[b,i,j,k]*(Ghw[b,j,k]+Ghc[b,i,k]) + x[b,k,i,j]*Gwc[b,i,k] ) / 3
__global__ __launch_bounds__(256) void combine_kernel(
    const float* __restrict__ x, const float* __restrict__ Ghw,
    const float* __restrict__ Ghc, const float* __restrict__ Gwc,
    float* __restrict__ out) {
  __shared__ float t[32][33];
  const int blk = blockIdx.x;
  const int kt = blk & 7, jt = (blk >> 3) & 7, i = (blk >> 6) & 255, b = blk >> 14;
  const int k0 = kt << 5, j0 = jt << 5;
  const int rowi = threadIdx.x >> 3;
  const int col4 = (threadIdx.x & 7) << 2;
  {
    float4 v = *(const float4*)(x + ((size_t)b << 24) + ((size_t)(k0 + rowi) << 16) +
                                ((size_t)i << 8) + j0 + col4);
    t[rowi][col4 + 0] = v.x;
    t[rowi][col4 + 1] = v.y;
    t[rowi][col4 + 2] = v.z;
    t[rowi][col4 + 3] = v.w;
  }
  __syncthreads();
  const int jj = rowi;
  const int k = k0 + col4;
  const size_t gik = (((size_t)(b << 8) + i) << 8) + k;
  const float4 ghc = *(const float4*)(Ghc + gik);
  const float4 gwc = *(const float4*)(Gwc + gik);
  const size_t base = ((size_t)b << 24) + ((size_t)i << 16) + ((size_t)(j0 + jj) << 8) + k;
  const float4 xv = *(const float4*)(x + base);
  const float4 ghw = *(const float4*)(Ghw + ((size_t)b << 16) + ((size_t)(j0 + jj) << 8) + k);
  const float third = 1.f / 3.f;
  float4 r;
  r.x = (xv.x * (ghw.x + ghc.x) + t[col4 + 0][jj] * gwc.x) * third;
  r.y = (xv.y * (ghw.y + ghc.y) + t[col4 + 1][jj] * gwc.y) * third;
  r.z = (xv.z * (ghw.z + ghc.z) + t[col4 + 2][jj] * gwc.z) * third;
  r.w = (xv.w * (ghw.w + ghc.w) + t[col4 + 3][jj] * gwc.w) * third;
  *(float4*)(out + base) = r;
}

extern "C" void kernel_launch(void* const* d_in, const int* in_sizes, int n_in,
                              void* d_out, int out_size, void* d_ws, size_t ws_size,
                              hipStream_t stream) {
  const float* x    = (const float*)d_in[0];
  const float* w_hw = (const float*)d_in[1];
  const float* g_hw = (const float*)d_in[2];
  const float* b_hw = (const float*)d_in[3];
  const float* m_hw = (const float*)d_in[4];
  const float* v_hw = (const float*)d_in[5];
  const float* w_hc = (const float*)d_in[6];
  const float* g_hc = (const float*)d_in[7];
  const float* b_hc = (const float*)d_in[8];
  const float* m_hc = (const float*)d_in[9];
  const float* v_hc = (const float*)d_in[10];
  const float* w_wc = (const float*)d_in[11];
  const float* g_wc = (const float*)d_in[12];
  const float* b_wc = (const float*)d_in[13];
  const float* m_wc = (const float*)d_in[14];
  const float* v_wc = (const float*)d_in[15];

  const int B = in_sizes[0] / NNN; // 2
  const int BN = B * N;
  const size_t plane = (size_t)B * NN;
  float* ws = (float*)d_ws;
  float* zAmax   = ws + 0 * plane;
  float* zAmean  = ws + 1 * plane;
  float* zBmax   = ws + 2 * plane;
  float* zBmean  = ws + 3 * plane;
  float* zCTmax  = ws + 4 * plane;
  float* zCTmean = ws + 5 * plane;
  float* GhwP    = ws + 6 * plane;
  float* GhcP    = ws + 7 * plane;
  float* GwcP    = ws + 8 * plane;

  // partials parked in d_out (consumed by folds before combine overwrites)
  float* pA = (float*)d_out;                       // B*32*2*NN floats (33.6 MB)
  float* pB = pA + (size_t)B * 32 * 2 * NN;        // B*N*8*2*N floats (8.4 MB)

  reduce_dense_kernel<<<B * 256, 256, 0, stream>>>(x, pA, pB, zCTmax, zCTmean);
  fold_a_kernel<<<B * NN / 256, 256, 0, stream>>>(pA, zAmax, zAmean);
  fold_b_kernel<<<BN, 256, 0, stream>>>(pB, zBmax, zBmean);

  conv_gate3_kernel<<<3 * BN, 256, 0, stream>>>(
      zAmax, zAmean, zBmax, zBmean, zCTmax, zCTmean,
      w_hw, g_hw, b_hw, m_hw, v_hw,
      w_hc, g_hc, b_hc, m_hc, v_hc,
      w_wc, g_wc, b_wc, m_wc, v_wc,
      GhwP, GhcP, GwcP, BN);

  combine_kernel<<<B * N * 64, 256, 0, stream>>>(x, GhwP, GhcP, GwcP, (float*)d_out);
}

// Round 11
// 128.853 us; speedup vs baseline: 1.1087x; 1.0122x over previous
//
#include <hip/hip_runtime.h>
#include <math.h>

#define N 256
#define NN (N * N)      // 65536
#define NNN (N * N * N) // 16777216

__device__ inline float4 f4max(float4 a, float4 b) {
  return make_float4(fmaxf(a.x, b.x), fmaxf(a.y, b.y), fmaxf(a.z, b.z), fmaxf(a.w, b.w));
}
__device__ inline float4 f4add(float4 a, float4 b) {
  return make_float4(a.x + b.x, a.y + b.y, a.z + b.z, a.w + b.w);
}

// ===== stream_a: PURE LINEAR device-wide pass over x =====
// 1024 blocks x 256 threads x f4 = 1M floats = 16 c-planes per hop; 32 hops.
// Device-wide access order is strictly ascending addresses (fillBuffer pattern).
// Thread (blk,tid): fixed (c0 = blk>>6, h = (blk&63)*4 + wave, w4 = lane*4);
// hop k reads c = c0 + (k&15)*16 of batch b = k>>4.
//   zA: in-register elementwise acc over the thread's 16 c-samples per b
//       -> pAm/pAs[c0][b][h][w] (16-group partials, folded in fold_a)
//   zCT: per-wave w-fold of its 1KB row (3 shfl levels -> 8 LDS partials),
//       final fold after loop -> zCT[b][c][h] complete (transposed layout)
__global__ __launch_bounds__(256) void stream_a_kernel(
    const float* __restrict__ x,
    float* __restrict__ pAm, float* __restrict__ pAs,
    float* __restrict__ zCTmax, float* __restrict__ zCTmean, int B) {
  __shared__ float pms[128][9][2];  // [hop*4+wave][8 partials pad 9][m,s]
  const int tid = threadIdx.x;
  const int lane = tid & 63;
  const int g = tid >> 6;            // wave 0..3
  const int blk = blockIdx.x;        // [0,1024)
  const int c0 = blk >> 6;           // [0,16)
  const int hbase = (blk & 63) << 2; // h of wave0
  const int h = hbase + g;
  const int w4 = lane << 2;
  const int KB = 16 * B;             // hops (32 for B=2)
  const float* base = x + (size_t)c0 * NN + (size_t)h * N + w4;

  const float4 NEG = make_float4(-INFINITY, -INFINITY, -INFINITY, -INFINITY);
  const float4 ZERO = make_float4(0.f, 0.f, 0.f, 0.f);
  float4 m4 = NEG, s4 = ZERO;

#pragma unroll 8
  for (int k = 0; k < KB; ++k) {
    const int b = k >> 4;
    const int kc = k & 15;
    float4 v = *(const float4*)(base + (size_t)b * NNN + (size_t)(kc * 16) * NN);
    // zA register acc
    m4 = f4max(m4, v);
    s4 = f4add(s4, v);
    // zCT partials: in-lane fold + 3 shfl levels -> 8 per-row partials
    float m = fmaxf(fmaxf(v.x, v.y), fmaxf(v.z, v.w));
    float s = (v.x + v.y) + (v.z + v.w);
    m = fmaxf(m, __shfl_xor(m, 1));
    s += __shfl_xor(s, 1);
    m = fmaxf(m, __shfl_xor(m, 2));
    s += __shfl_xor(s, 2);
    m = fmaxf(m, __shfl_xor(m, 4));
    s += __shfl_xor(s, 4);
    if ((lane & 7) == 0) {
      pms[k * 4 + g][lane >> 3][0] = m;
      pms[k * 4 + g][lane >> 3][1] = s;
    }
    // end of this b: flush zA partial, reset
    if (kc == 15) {
      const size_t o = (size_t)(c0 * B + b) * NN + (size_t)h * N + w4;
      *(float4*)(pAm + o) = m4;
      *(float4*)(pAs + o) = s4;
      m4 = NEG;
      s4 = ZERO;
    }
  }
  __syncthreads();
  // finalize zCT: row t = (hop, wave)
  if (tid < 4 * KB) {
    float m = pms[tid][0][0];
    float s = pms[tid][0][1];
#pragma unroll
    for (int i = 1; i < 8; ++i) {
      m = fmaxf(m, pms[tid][i][0]);
      s += pms[tid][i][1];
    }
    const int k = tid >> 2;
    const int b = k >> 4;
    const int c = c0 + (k & 15) * 16;
    const int hr = hbase + (tid & 3);
    const size_t o = ((size_t)(b * N + c) << 8) + hr;
    zCTmax[o] = m;
    zCTmean[o] = s * (1.f / 256.f);
  }
}

// ===== stream_b: zB[b][c][w] = max/mean over h. Contiguous 256KB plane/block. =====
// Pure f4max/f4add in registers (no shfl), 4-wave LDS fold. L3-warm after stream_a.
__global__ __launch_bounds__(256) void stream_b_kernel(
    const float* __restrict__ x,
    float* __restrict__ zBmax, float* __restrict__ zBmean) {
  __shared__ float gm[4][N];
  __shared__ float gs[4][N];
  const int lane = threadIdx.x & 63;
  const int g = threadIdx.x >> 6;
  const int bc = blockIdx.x;   // b*N + c
  const int b = bc >> 8, c = bc & 255;
  const int w4 = lane << 2;
  const float* p = x + (size_t)b * NNN + (size_t)c * NN + (size_t)(g * 64) * N + w4;
  float4 m = make_float4(-INFINITY, -INFINITY, -INFINITY, -INFINITY);
  float4 s = make_float4(0.f, 0.f, 0.f, 0.f);
#pragma unroll 8
  for (int r = 0; r < 64; ++r) {
    float4 v = *(const float4*)(p + (size_t)r * N);
    m = f4max(m, v);
    s = f4add(s, v);
  }
  *(float4*)&gm[g][w4] = m;
  *(float4*)&gs[g][w4] = s;
  __syncthreads();
  const int t = threadIdx.x;
  float mm = fmaxf(fmaxf(gm[0][t], gm[1][t]), fmaxf(gm[2][t], gm[3][t]));
  float ss = (gs[0][t] + gs[1][t] + gs[2][t] + gs[3][t]) * (1.f / 256.f);
  zBmax[(size_t)bc * N + t] = mm;
  zBmean[(size_t)bc * N + t] = ss;
}

// ===== fold_a: fold 16 c-group partials -> zA[b][h][w] =====
__global__ __launch_bounds__(256) void fold_a_kernel(
    const float* __restrict__ pAm, const float* __restrict__ pAs,
    float* __restrict__ zAmax, float* __restrict__ zAmean, int B) {
  const int idx = blockIdx.x * 256 + threadIdx.x;  // f4 slots: B*NN/4
  const int w4 = (idx & 63) << 2;
  const int h = (idx >> 6) & 255;
  const int b = idx >> 14;
  const size_t o0 = (size_t)b * NN + (size_t)h * N + w4;
  float4 m = *(const float4*)(pAm + o0);
  float4 s = *(const float4*)(pAs + o0);
#pragma unroll
  for (int c0 = 1; c0 < 16; ++c0) {
    const size_t o = (size_t)(c0 * B) * NN + o0;
    m = f4max(m, *(const float4*)(pAm + o));
    s = f4add(s, *(const float4*)(pAs + o));
  }
  s.x *= (1.f / 256.f); s.y *= (1.f / 256.f); s.z *= (1.f / 256.f); s.w *= (1.f / 256.f);
  const size_t pos = (size_t)(b * N + h) * N + w4;
  *(float4*)(zAmax + pos) = m;
  *(float4*)(zAmean + pos) = s;
}

// -------- fused 7x7 conv (2ch->1) + BN + sigmoid for ALL THREE gates --------
// branch 0 (hw): zA in [b][h][w], out Ghw[b][h][w]
// branch 1 (hc): zB in [b][c][w], out Ghc[b][c][w]
// branch 2 (wc): zCT TRANSPOSED [b][c][h]; block=(b,c), thread=h, out Gwc[b][h][c]
__global__ __launch_bounds__(256) void conv_gate3_kernel(
    const float* __restrict__ zAmax, const float* __restrict__ zAmean,
    const float* __restrict__ zBmax, const float* __restrict__ zBmean,
    const float* __restrict__ zCTmax, const float* __restrict__ zCTmean,
    const float* __restrict__ w_hw, const float* __restrict__ g_hw,
    const float* __restrict__ b_hw, const float* __restrict__ m_hw,
    const float* __restrict__ v_hw,
    const float* __restrict__ w_hc, const float* __restrict__ g_hc,
    const float* __restrict__ b_hc, const float* __restrict__ m_hc,
    const float* __restrict__ v_hc,
    const float* __restrict__ w_wc, const float* __restrict__ g_wc,
    const float* __restrict__ b_wc, const float* __restrict__ m_wc,
    const float* __restrict__ v_wc,
    float* __restrict__ Ghw, float* __restrict__ Ghc, float* __restrict__ Gwc,
    int BN) {
  const int branch = blockIdx.x / BN;
  const int bp = blockIdx.x - branch * BN;  // b*N + (p or c)
  const int b = bp >> 8;
  const size_t boff = (size_t)b * NN;

  if (branch == 2) {
    const int c = bp & 255;
    const int h = threadIdx.x;
    const float* zm = zCTmax + boff;
    const float* za = zCTmean + boff;
    float y = 0.f;
#pragma unroll
    for (int dc = 0; dc < 7; ++dc) {
      const int cc = c + dc - 3;
      if ((unsigned)cc < N) {
#pragma unroll
        for (int dh = 0; dh < 7; ++dh) {
          const int hh = h + dh - 3;
          if ((unsigned)hh < N) {
            const int idx = cc * N + hh;
            y += zm[idx] * w_wc[dh * 7 + dc] + za[idx] * w_wc[49 + dh * 7 + dc];
          }
        }
      }
    }
    const float scale = g_wc[0] * rsqrtf(v_wc[0] + 1e-5f);
    const float yb = (y - m_wc[0]) * scale + b_wc[0];
    Gwc[boff + (size_t)h * N + c] = 1.f / (1.f + __expf(-yb));
    return;
  }

  const int p = bp & 255;
  const int q = threadIdx.x;
  const float *zm, *za, *wt, *gg, *bb, *mm, *vv;
  float* gate;
  if (branch == 0) {
    zm = zAmax; za = zAmean;
    wt = w_hw; gg = g_hw; bb = b_hw; mm = m_hw; vv = v_hw; gate = Ghw;
  } else {
    zm = zBmax; za = zBmean;
    wt = w_hc; gg = g_hc; bb = b_hc; mm = m_hc; vv = v_hc; gate = Ghc;
  }
  zm += boff;
  za += boff;
  float y = 0.f;
#pragma unroll
  for (int dh = 0; dh < 7; ++dh) {
    const int pp = p + dh - 3;
    if ((unsigned)pp < N) {
#pragma unroll
      for (int dw = 0; dw < 7; ++dw) {
        const int qq = q + dw - 3;
        if ((unsigned)qq < N) {
          const int idx = pp * N + qq;
          y += zm[idx] * wt[dh * 7 + dw] + za[idx] * wt[49 + dh * 7 + dw];
        }
      }
    }
  }
  const float scale = gg[0] * rsqrtf(vv[0] + 1e-5f);
  const float yb = (y - mm[0]) * scale + bb[0];
  gate[boff + (size_t)p * N + q] = 1.f / (1.f + __expf(-yb));
}

// -------- final combine --------
// out[b,i,j,k] = ( x[b,i,j,k]*(Ghw[b,j,k]+Ghc[b,i,k]) + x[b,k,i,j]*Gwc[b,i,k] ) / 3
__global__ __launch_bounds__(256) void combine_kernel(
    const float* __restrict__ x, const float* __restrict__ Ghw,
    const float* __restrict__ Ghc, const float* __restrict__ Gwc,
    float* __restrict__ out) {
  __shared__ float t[32][33];
  const int blk = blockIdx.x;
  const int kt = blk & 7, jt = (blk >> 3) & 7, i = (blk >> 6) & 255, b = blk >> 14;
  const int k0 = kt << 5, j0 = jt << 5;
  const int rowi = threadIdx.x >> 3;
  const int col4 = (threadIdx.x & 7) << 2;
  {
    float4 v = *(const float4*)(x + ((size_t)b << 24) + ((size_t)(k0 + rowi) << 16) +
                                ((size_t)i << 8) + j0 + col4);
    t[rowi][col4 + 0] = v.x;
    t[rowi][col4 + 1] = v.y;
    t[rowi][col4 + 2] = v.z;
    t[rowi][col4 + 3] = v.w;
  }
  __syncthreads();
  const int jj = rowi;
  const int k = k0 + col4;
  const size_t gik = (((size_t)(b << 8) + i) << 8) + k;
  const float4 ghc = *(const float4*)(Ghc + gik);
  const float4 gwc = *(const float4*)(Gwc + gik);
  const size_t base = ((size_t)b << 24) + ((size_t)i << 16) + ((size_t)(j0 + jj) << 8) + k;
  const float4 xv = *(const float4*)(x + base);
  const float4 ghw = *(const float4*)(Ghw + ((size_t)b << 16) + ((size_t)(j0 + jj) << 8) + k);
  const float third = 1.f / 3.f;
  float4 r;
  r.x = (xv.x * (ghw.x + ghc.x) + t[col4 + 0][jj] * gwc.x) * third;
  r.y = (xv.y * (ghw.y + ghc.y) + t[col4 + 1][jj] * gwc.y) * third;
  r.z = (xv.z * (ghw.z + ghc.z) + t[col4 + 2][jj] * gwc.z) * third;
  r.w = (xv.w * (ghw.w + ghc.w) + t[col4 + 3][jj] * gwc.w) * third;
  *(float4*)(out + base) = r;
}

extern "C" void kernel_launch(void* const* d_in, const int* in_sizes, int n_in,
                              void* d_out, int out_size, void* d_ws, size_t ws_size,
                              hipStream_t stream) {
  const float* x    = (const float*)d_in[0];
  const float* w_hw = (const float*)d_in[1];
  const float* g_hw = (const float*)d_in[2];
  const float* b_hw = (const float*)d_in[3];
  const float* m_hw = (const float*)d_in[4];
  const float* v_hw = (const float*)d_in[5];
  const float* w_hc = (const float*)d_in[6];
  const float* g_hc = (const float*)d_in[7];
  const float* b_hc = (const float*)d_in[8];
  const float* m_hc = (const float*)d_in[9];
  const float* v_hc = (const float*)d_in[10];
  const float* w_wc = (const float*)d_in[11];
  const float* g_wc = (const float*)d_in[12];
  const float* b_wc = (const float*)d_in[13];
  const float* m_wc = (const float*)d_in[14];
  const float* v_wc = (const float*)d_in[15];

  const int B = in_sizes[0] / NNN; // 2
  const int BN = B * N;
  const size_t plane = (size_t)B * NN;
  float* ws = (float*)d_ws;
  float* zAmax   = ws + 0 * plane;
  float* zAmean  = ws + 1 * plane;
  float* zBmax   = ws + 2 * plane;
  float* zBmean  = ws + 3 * plane;
  float* zCTmax  = ws + 4 * plane;
  float* zCTmean = ws + 5 * plane;
  float* GhwP    = ws + 6 * plane;
  float* GhcP    = ws + 7 * plane;
  float* GwcP    = ws + 8 * plane;

  // zA 16-group partials parked in d_out (consumed by fold_a before combine)
  float* pAm = (float*)d_out;              // 16*B*NN floats (8.4 MB)
  float* pAs = pAm + (size_t)16 * B * NN;  // 8.4 MB

  stream_a_kernel<<<1024, 256, 0, stream>>>(x, pAm, pAs, zCTmax, zCTmean, B);
  stream_b_kernel<<<BN, 256, 0, stream>>>(x, zBmax, zBmean);
  fold_a_kernel<<<B * NN / 1024, 256, 0, stream>>>(pAm, pAs, zAmax, zAmean, B);

  conv_gate3_kernel<<<3 * BN, 256, 0, stream>>>(
      zAmax, zAmean, zBmax, zBmean, zCTmax, zCTmean,
      w_hw, g_hw, b_hw, m_hw, v_hw,
      w_hc, g_hc, b_hc, m_hc, v_hc,
      w_wc, g_wc, b_wc, m_wc, v_wc,
      GhwP, GhcP, GwcP, BN);

  combine_kernel<<<B * N * 64, 256, 0, stream>>>(x, GhwP, GhcP, GwcP, (float*)d_out);
}